// Round 2
// baseline (30.875 us; speedup 1.0000x reference)
//
#include <hip/hip_runtime.h>

#define S_DIM 4
#define F_DIM 4
#define E_DIM 65536
#define NCP   32
#define PDEG  3

// knots = concat(zeros(3), linspace(0,1,30), ones(3)) -> knot(i) = clamp((i-3)/29, 0, 1)
__device__ __forceinline__ float knotv(int i) {
    float t = (float)(i - PDEG) * (1.0f / (float)(NCP - PDEG));
    return fminf(fmaxf(t, 0.0f), 1.0f);
}

// Cox-de Boor p=3 basis + first derivative (scaled by p), fully unrolled.
__device__ __forceinline__ void basis_p3(float u, int span, float N0[4], float N1[4]) {
    float left[4], right[4];
    float ndu[4][4];
    ndu[0][0] = 1.0f;
#pragma unroll
    for (int j = 1; j <= PDEG; ++j) {
        left[j]  = u - knotv(span - j + 1);
        right[j] = knotv(span + j) - u;
        float saved = 0.0f;
#pragma unroll
        for (int r = 0; r < j; ++r) {
            float denom = right[r + 1] + left[j - r];
            ndu[j][r] = denom;
            float tmp = ndu[r][j - 1] * __builtin_amdgcn_rcpf(denom);
            ndu[r][j] = saved + right[r + 1] * tmp;
            saved = left[j - r] * tmp;
        }
        ndu[j][j] = saved;
    }
#pragma unroll
    for (int j = 0; j <= PDEG; ++j) N0[j] = ndu[j][PDEG];
    float inv3[3];
#pragma unroll
    for (int r = 0; r < PDEG; ++r) inv3[r] = __builtin_amdgcn_rcpf(ndu[PDEG][r]);
    N1[0] = -(float)PDEG * (ndu[0][PDEG - 1] * inv3[0]);
    N1[1] =  (float)PDEG * (ndu[0][PDEG - 1] * inv3[0] - ndu[1][PDEG - 1] * inv3[1]);
    N1[2] =  (float)PDEG * (ndu[1][PDEG - 1] * inv3[1] - ndu[2][PDEG - 1] * inv3[2]);
    N1[3] =  (float)PDEG * (ndu[2][PDEG - 1] * inv3[2]);
}

__global__ __launch_bounds__(256, 4) void nurbs_eval_kernel(
    const float* __restrict__ ep,   // (S,F,E,2)
    const float* __restrict__ cp,   // (S,F,NCP,NCP,3)
    float* __restrict__ out)        // points4 (S,F,E,4) then normals4 (S,F,E,4)
{
    __shared__ float4 g4[NCP * NCP];  // 16 KiB, xyz + pad -> aligned ds_read_b128 gathers

    const int sf  = blockIdx.y;
    const int tid = threadIdx.x;

    // Stage: thread t owns control points {t, t+256, t+512, t+768}.
    // ds_write instr k: lane t -> LDS quad (t & 7) -> conflict-free.
    {
        const float* src = cp + (size_t)sf * (NCP * NCP * 3);
#pragma unroll
        for (int k = 0; k < 4; ++k) {
            const int c = tid + 256 * k;
            const float* s = src + 3 * c;
            g4[c] = make_float4(s[0], s[1], s[2], 0.0f);
        }
    }
    __syncthreads();

    const int e   = blockIdx.x * 256 + tid;
    const int idx = sf * E_DIM + e;

    const float2 uv = ((const float2*)ep)[idx];
    const float u = uv.x, v = uv.y;

    int su = (int)floorf(u * (float)(NCP - PDEG)) + PDEG;
    su = min(max(su, PDEG), NCP - 1);
    int sv = (int)floorf(v * (float)(NCP - PDEG)) + PDEG;
    sv = min(max(sv, PDEG), NCP - 1);

    float bu0[4], bu1[4], bv0[4], bv1[4];
    basis_p3(u, su, bu0, bu1);
    basis_p3(v, sv, bv0, bv1);

    float px = 0.f, py = 0.f, pz = 0.f;
    float dux = 0.f, duy = 0.f, duz = 0.f;
    float dvx = 0.f, dvy = 0.f, dvz = 0.f;

    const int base_u = su - PDEG;
    const int base_v = sv - PDEG;

#pragma unroll
    for (int i = 0; i < 4; ++i) {
        const float4* row = &g4[(base_u + i) * NCP + base_v];
        float t0x = 0.f, t0y = 0.f, t0z = 0.f;   // sum_j g * bv0[j]
        float t1x = 0.f, t1y = 0.f, t1z = 0.f;   // sum_j g * bv1[j]
#pragma unroll
        for (int j = 0; j < 4; ++j) {
            const float4 gj = row[j];            // one ds_read_b128
            const float b0 = bv0[j], b1 = bv1[j];
            t0x = fmaf(gj.x, b0, t0x); t0y = fmaf(gj.y, b0, t0y); t0z = fmaf(gj.z, b0, t0z);
            t1x = fmaf(gj.x, b1, t1x); t1y = fmaf(gj.y, b1, t1y); t1z = fmaf(gj.z, b1, t1z);
        }
        px  = fmaf(bu0[i], t0x, px);  py  = fmaf(bu0[i], t0y, py);  pz  = fmaf(bu0[i], t0z, pz);
        dux = fmaf(bu1[i], t0x, dux); duy = fmaf(bu1[i], t0y, duy); duz = fmaf(bu1[i], t0z, duz);
        dvx = fmaf(bu0[i], t1x, dvx); dvy = fmaf(bu0[i], t1y, dvy); dvz = fmaf(bu0[i], t1z, dvz);
    }

    // normal = normalize(du x dv)
    float nx = duy * dvz - duz * dvy;
    float ny = duz * dvx - dux * dvz;
    float nz = dux * dvy - duy * dvx;
    const float nn = sqrtf(nx * nx + ny * ny + nz * nz) + 1e-12f;
    const float inv = __builtin_amdgcn_rcpf(nn);
    nx *= inv; ny *= inv; nz *= inv;

    float4* outv = (float4*)out;
    outv[idx] = make_float4(px, py, pz, 1.0f);
    outv[(size_t)S_DIM * F_DIM * E_DIM + idx] = make_float4(nx, ny, nz, 0.0f);
}

extern "C" void kernel_launch(void* const* d_in, const int* in_sizes, int n_in,
                              void* d_out, int out_size, void* d_ws, size_t ws_size,
                              hipStream_t stream) {
    const float* ep = (const float*)d_in[0];
    const float* cp = (const float*)d_in[1];
    float* out = (float*)d_out;

    dim3 grid(E_DIM / 256, S_DIM * F_DIM);
    dim3 block(256);
    hipLaunchKernelGGL(nurbs_eval_kernel, grid, block, 0, stream, ep, cp, out);
}

// Round 4
// 19.353 us; speedup vs baseline: 1.5953x; 1.5953x over previous
//
#include <hip/hip_runtime.h>

typedef __fp16 half2_t __attribute__((ext_vector_type(2)));

#define S_DIM 4
#define F_DIM 4
#define E_DIM 65536
#define NCP   32

union H2U { unsigned u; half2_t h; };

__device__ __forceinline__ unsigned pkh(float a, float b) {
    H2U c; c.h = __builtin_amdgcn_cvt_pkrtz(a, b);
    return c.u;
}
__device__ __forceinline__ half2_t ash2(unsigned u) {
    H2U c; c.u = u;
    return c.h;
}

// Cubic clamped-uniform basis + derivative (x3), trimmed knot math.
// fs = float(span-3) in [0,28]; knots(i) = clamp((i-3)/29, 0, 1).
__device__ __forceinline__ void basis3(float u, float fs, float* N0, float* N1) {
    const float h = 1.0f / 29.0f;
    const float b = fs * h;
    const float L1 = u - b;                                // knot(span)   never clamped
    const float L2 = u - fmaxf(b - h, 0.0f);               // knot(span-1) lo-clamp
    const float L3 = u - fmaxf(b - 2.0f * h, 0.0f);        // knot(span-2) lo-clamp
    const float R1 = (b + h) - u;                          // knot(span+1) never clamped
    const float R2 = fminf(b + 2.0f * h, 1.0f) - u;        // knot(span+2) hi-clamp
    const float R3 = fminf(b + 3.0f * h, 1.0f) - u;        // knot(span+3) hi-clamp
    // j=1
    const float i10 = __builtin_amdgcn_rcpf(R1 + L1);
    const float v01 = R1 * i10;            // ndu[0][1]
    const float v11 = L1 * i10;            // ndu[1][1]
    // j=2
    const float i20 = __builtin_amdgcn_rcpf(R1 + L2);
    float t = v01 * i20;
    const float v02 = R1 * t;              // ndu[0][2]
    float s = L2 * t;
    const float i21 = __builtin_amdgcn_rcpf(R2 + L1);
    t = v11 * i21;
    const float v12 = s + R2 * t;          // ndu[1][2]
    const float v22 = L1 * t;              // ndu[2][2]
    // j=3
    const float i30 = __builtin_amdgcn_rcpf(R1 + L3);
    t = v02 * i30;
    N0[0] = R1 * t;
    s = L3 * t;
    const float i31 = __builtin_amdgcn_rcpf(R2 + L2);
    t = v12 * i31;
    N0[1] = s + R2 * t;
    s = L2 * t;
    const float i32 = __builtin_amdgcn_rcpf(R3 + L1);
    t = v22 * i32;
    N0[2] = s + R3 * t;
    N0[3] = L1 * t;
    // first derivative * p
    const float a0 = v02 * i30, a1 = v12 * i31, a2 = v22 * i32;
    N1[0] = -3.0f * a0;
    N1[1] = 3.0f * (a0 - a1);
    N1[2] = 3.0f * (a1 - a2);
    N1[3] = 3.0f * a2;
}

__global__ __launch_bounds__(256) void nurbs_eval_kernel(
    const float* __restrict__ ep,   // (S,F,E,2)
    const float* __restrict__ cp,   // (S,F,NCP,NCP,3)
    float* __restrict__ out)        // points4 then normals4
{
    // E_c[u][v] = half2(c[u][v], c[u][v+1]); 3 comps, row stride 33 words.
    __shared__ unsigned sm[3 * 32 * 33];   // 12.4 KiB

    const int sf  = blockIdx.y;
    const int tid = threadIdx.x;

    // ---- Stage: thread (u = tid>>3, m = tid&7) builds E[u][4m..4m+3] ----
    {
        const int u = tid >> 3, m = tid & 7;
        const float* rowp = cp + ((size_t)sf * 1024 + (size_t)u * 32) * 3;
        const int o = 12 * m;
        const float4 Ld0 = *(const float4*)(rowp + o);
        const float4 Ld1 = *(const float4*)(rowp + o + 4);
        const float4 Ld2 = *(const float4*)(rowp + o + 8);
        // m==7: floats 96..99 would read past the row; they only feed unused E[u][31].
        const float4 Ld3 = *(const float4*)(rowp + ((m == 7) ? 80 : (o + 12)));
        float f[16];
        f[0]=Ld0.x; f[1]=Ld0.y; f[2]=Ld0.z; f[3]=Ld0.w;
        f[4]=Ld1.x; f[5]=Ld1.y; f[6]=Ld1.z; f[7]=Ld1.w;
        f[8]=Ld2.x; f[9]=Ld2.y; f[10]=Ld2.z; f[11]=Ld2.w;
        f[12]=Ld3.x; f[13]=Ld3.y; f[14]=Ld3.z; f[15]=Ld3.w;
        unsigned* E0 = sm;
        unsigned* E1 = sm + 1056;
        unsigned* E2 = sm + 2112;
#pragma unroll
        for (int e = 0; e < 4; ++e) {
            const int v = 4 * m + e;
            const int a = u * 33 + v;      // (u + 4m) spread -> conflict-free writes
            E0[a] = pkh(f[3*e+0], f[3*e+3]);
            E1[a] = pkh(f[3*e+1], f[3*e+4]);
            E2[a] = pkh(f[3*e+2], f[3*e+5]);
        }
    }
    __syncthreads();

    const int e   = blockIdx.x * 256 + tid;
    const int idx = sf * E_DIM + e;

    const float2 uvp = ((const float2*)ep)[idx];
    const float uu = uvp.x, vv = uvp.y;

    const float fsu = fminf(fmaxf(floorf(uu * 29.0f), 0.0f), 28.0f);
    const float fsv = fminf(fmaxf(floorf(vv * 29.0f), 0.0f), 28.0f);
    const int bu = (int)fsu, bv = (int)fsv;

    float bu0[4], bu1[4], bv0[4], bv1[4];
    basis3(uu, fsu, bu0, bu1);
    basis3(vv, fsv, bv0, bv1);

    const half2_t w00 = __builtin_amdgcn_cvt_pkrtz(bv0[0], bv0[1]);
    const half2_t w01 = __builtin_amdgcn_cvt_pkrtz(bv0[2], bv0[3]);
    const half2_t w10 = __builtin_amdgcn_cvt_pkrtz(bv1[0], bv1[1]);
    const half2_t w11 = __builtin_amdgcn_cvt_pkrtz(bv1[2], bv1[3]);

    const unsigned* E0 = sm;
    const unsigned* E1 = sm + 1056;
    const unsigned* E2 = sm + 2112;
    const int base = 33 * bu + bv;

    float px=0.f, py=0.f, pz=0.f;
    float dux=0.f, duy=0.f, duz=0.f;
    float dvx=0.f, dvy=0.f, dvz=0.f;

#pragma unroll
    for (int i = 0; i < 4; ++i) {
        const int a = base + 33 * i;
        const half2_t x0 = ash2(E0[a]), x1 = ash2(E0[a + 2]);
        const half2_t y0 = ash2(E1[a]), y1 = ash2(E1[a + 2]);
        const half2_t z0 = ash2(E2[a]), z1 = ash2(E2[a + 2]);
        const float t0x = __builtin_amdgcn_fdot2(x1, w01, __builtin_amdgcn_fdot2(x0, w00, 0.0f, false), false);
        const float t1x = __builtin_amdgcn_fdot2(x1, w11, __builtin_amdgcn_fdot2(x0, w10, 0.0f, false), false);
        const float t0y = __builtin_amdgcn_fdot2(y1, w01, __builtin_amdgcn_fdot2(y0, w00, 0.0f, false), false);
        const float t1y = __builtin_amdgcn_fdot2(y1, w11, __builtin_amdgcn_fdot2(y0, w10, 0.0f, false), false);
        const float t0z = __builtin_amdgcn_fdot2(z1, w01, __builtin_amdgcn_fdot2(z0, w00, 0.0f, false), false);
        const float t1z = __builtin_amdgcn_fdot2(z1, w11, __builtin_amdgcn_fdot2(z0, w10, 0.0f, false), false);
        px  = fmaf(bu0[i], t0x, px);  py  = fmaf(bu0[i], t0y, py);  pz  = fmaf(bu0[i], t0z, pz);
        dux = fmaf(bu1[i], t0x, dux); duy = fmaf(bu1[i], t0y, duy); duz = fmaf(bu1[i], t0z, duz);
        dvx = fmaf(bu0[i], t1x, dvx); dvy = fmaf(bu0[i], t1y, dvy); dvz = fmaf(bu0[i], t1z, dvz);
    }

    float nx = duy * dvz - duz * dvy;
    float ny = duz * dvx - dux * dvz;
    float nz = dux * dvy - duy * dvx;
    float n2 = nx * nx + ny * ny + nz * nz;
    const float du2 = dux*dux + duy*duy + duz*duz;
    const float dv2 = dvx*dvx + dvy*dvy + dvz*dvz;

    // Near-parallel du,dv: f16 noise amplified by 1/sin(theta) -> redo normal in f32.
    if (n2 < 2e-3f * (du2 * dv2)) {
        const float* patch = cp + (size_t)sf * 3072;
        float DUX=0.f, DUY=0.f, DUZ=0.f, DVX=0.f, DVY=0.f, DVZ=0.f;
#pragma unroll
        for (int i = 0; i < 4; ++i) {
            float s0x=0.f, s0y=0.f, s0z=0.f, s1x=0.f, s1y=0.f, s1z=0.f;
#pragma unroll
            for (int j = 0; j < 4; ++j) {
                const float* p = patch + (((bu + i) * 32) + (bv + j)) * 3;
                const float gx = p[0], gy = p[1], gz = p[2];
                s0x = fmaf(gx, bv0[j], s0x); s0y = fmaf(gy, bv0[j], s0y); s0z = fmaf(gz, bv0[j], s0z);
                s1x = fmaf(gx, bv1[j], s1x); s1y = fmaf(gy, bv1[j], s1y); s1z = fmaf(gz, bv1[j], s1z);
            }
            DUX = fmaf(bu1[i], s0x, DUX); DUY = fmaf(bu1[i], s0y, DUY); DUZ = fmaf(bu1[i], s0z, DUZ);
            DVX = fmaf(bu0[i], s1x, DVX); DVY = fmaf(bu0[i], s1y, DVY); DVZ = fmaf(bu0[i], s1z, DVZ);
        }
        nx = DUY * DVZ - DUZ * DVY;
        ny = DUZ * DVX - DUX * DVZ;
        nz = DUX * DVY - DUY * DVX;
        n2 = nx * nx + ny * ny + nz * nz;
    }

    const float inv = __builtin_amdgcn_rcpf(sqrtf(n2) + 1e-12f);
    nx *= inv; ny *= inv; nz *= inv;

    float4* outv = (float4*)out;
    outv[idx] = make_float4(px, py, pz, 1.0f);
    outv[(size_t)S_DIM * F_DIM * E_DIM + idx] = make_float4(nx, ny, nz, 0.0f);
}

extern "C" void kernel_launch(void* const* d_in, const int* in_sizes, int n_in,
                              void* d_out, int out_size, void* d_ws, size_t ws_size,
                              hipStream_t stream) {
    const float* ep = (const float*)d_in[0];
    const float* cp = (const float*)d_in[1];
    float* out = (float*)d_out;

    dim3 grid(E_DIM / 256, S_DIM * F_DIM);
    dim3 block(256);
    hipLaunchKernelGGL(nurbs_eval_kernel, grid, block, 0, stream, ep, cp, out);
}